// Round 5
// baseline (558.174 us; speedup 1.0000x reference)
//
#include <hip/hip_runtime.h>
#include <cstdint>

typedef _Float16 f16;
typedef __attribute__((ext_vector_type(8)))  f16   v8h;
typedef __attribute__((ext_vector_type(16))) float v16f;
typedef unsigned short ushort_t;

#define N_TOK  65536
#define DIM    256
#define K_CB   4096
#define BN     64          // tokens per block
#define KC     1024        // codes per kci (8 waves x 128)
#define NKCI   4           // K_CB / KC
#define NCHUNK 64          // NKCI * 16 d-chunks
#define MARGIN_S 2.0e-3f   // 10-sigma of fp16-lo-drop error (s-space)

#define MFMA(a,b,c) __builtin_amdgcn_mfma_f32_32x32x16_f16(a,b,c,0,0,0)

// ---------------------------------------------------------------- b2 = ||c_k||^2 (fp32)
__global__ void b2_kernel(const float* __restrict__ cb, float* __restrict__ b2) {
    int gid = blockIdx.x * blockDim.x + threadIdx.x;
    int w = gid >> 6, lane = gid & 63;
    if (w >= K_CB) return;
    float4 v = reinterpret_cast<const float4*>(cb + (size_t)w * DIM)[lane];
    float s = (v.x * v.x + v.y * v.y) + (v.z * v.z + v.w * v.w);
#pragma unroll
    for (int off = 1; off < 64; off <<= 1) s += __shfl_xor(s, off, 64);
    if (lane == 0) b2[w] = s;
}

// ---------------------------------------------------------------- pack cb -> fp16-hi panels
// chunk = kci*16 + ci (64 chunks, 32 KB each): [wave 8][dgrp 2][128 codes][8 d] f16
__global__ void pack_cb(const float* __restrict__ cb, ushort_t* __restrict__ cbws) {
    int gid = blockIdx.x * 256 + threadIdx.x;          // 0..131071
    int k = gid >> 5, grp = gid & 31;                  // grp = d/8
    int ci = grp >> 1, dgrp = grp & 1;
    int kci = k >> 10, code = k & 1023;
    int wid_s = code >> 7, cloc = code & 127;
    const float* src = cb + (size_t)k * DIM + grp * 8;
    float4 v0 = *(const float4*)(src);
    float4 v1 = *(const float4*)(src + 4);
    float f[8] = {v0.x, v0.y, v0.z, v0.w, v1.x, v1.y, v1.z, v1.w};
    v8h hv;
#pragma unroll
    for (int e = 0; e < 8; ++e) hv[e] = (f16)f[e];
    size_t base = ((size_t)(kci * 16 + ci)) * 16384 + wid_s * 2048 + dgrp * 1024 + cloc * 8;
    *(v8h*)(cbws + base) = hv;
}

// ---------------------------------------------------------------- fused MFMA dist+argmax(s)
// s[n][k] = dot(x_n, ch_k) - b2[k]/2 (x = xh+xl exact in fp16 pair; codes hi-only).
__global__ __launch_bounds__(512, 2) void argmin_kernel(
    const float* __restrict__ x, const ushort_t* __restrict__ cbws,
    const float* __restrict__ b2, int* __restrict__ bestIdx,
    int* __restrict__ flagCnt, int* __restrict__ flagList)
{
    __shared__ __align__(16) f16 Xh[32 * 64 * 8];   // 32 KB: [dgrpIdx 32][token 64][8 d]
    __shared__ __align__(16) f16 Xl[32 * 64 * 8];   // 32 KB

    const int tid   = threadIdx.x;
    const int wid   = tid >> 6;
    const int lane  = tid & 63;
    const int l31   = lane & 31;
    const int lhalf = lane >> 5;
    const int n0    = blockIdx.x * BN;

    // ---- stage x tile (once): fp32 -> fp16 hi/lo, d-subtiled
    {
        const int token = tid >> 3, dseg = tid & 7;
        const float4* xr = (const float4*)(x + (size_t)(n0 + token) * DIM + dseg * 32);
#pragma unroll
        for (int sgrp = 0; sgrp < 4; ++sgrp) {
            float4 a = xr[2 * sgrp], b = xr[2 * sgrp + 1];
            float f[8] = {a.x, a.y, a.z, a.w, b.x, b.y, b.z, b.w};
            v8h hv, lv;
#pragma unroll
            for (int e = 0; e < 8; ++e) {
                f16 h = (f16)f[e];
                hv[e] = h; lv[e] = (f16)(f[e] - (float)h);
            }
            int off = ((dseg * 4 + sgrp) * 64 + token) * 8;
            *(v8h*)(Xh + off) = hv;
            *(v8h*)(Xl + off) = lv;
        }
    }
    __syncthreads();

    // per-lane A source: wave's 128-code slice; chunk stride 16384 ushorts (32 KB)
    const ushort_t* ap = cbws + (size_t)wid * 2048 + (size_t)lhalf * 1024 + (size_t)l31 * 8;

#define LOAD_A(A, g_) do { \
        const ushort_t* p_ = ap + (size_t)(g_) * 16384; \
        A##0 = *(const v8h*)(p_);       A##1 = *(const v8h*)(p_ + 256); \
        A##2 = *(const v8h*)(p_ + 512); A##3 = *(const v8h*)(p_ + 768); } while (0)
#define READ_B(B, g_) do { \
        int boff_ = ((((g_) & 15) * 2 + lhalf) * 64 + l31) * 8; \
        B##0 = *(const v8h*)(Xh + boff_); B##1 = *(const v8h*)(Xh + boff_ + 256); \
        B##2 = *(const v8h*)(Xl + boff_); B##3 = *(const v8h*)(Xl + boff_ + 256); } while (0)
#define MFMA16(A, B) do { \
        acc[0][0] = MFMA(A##0, B##0, acc[0][0]); \
        acc[0][1] = MFMA(A##0, B##1, acc[0][1]); \
        acc[1][0] = MFMA(A##1, B##0, acc[1][0]); \
        acc[1][1] = MFMA(A##1, B##1, acc[1][1]); \
        acc[2][0] = MFMA(A##2, B##0, acc[2][0]); \
        acc[2][1] = MFMA(A##2, B##1, acc[2][1]); \
        acc[3][0] = MFMA(A##3, B##0, acc[3][0]); \
        acc[3][1] = MFMA(A##3, B##1, acc[3][1]); \
        acc[0][0] = MFMA(A##0, B##2, acc[0][0]); \
        acc[0][1] = MFMA(A##0, B##3, acc[0][1]); \
        acc[1][0] = MFMA(A##1, B##2, acc[1][0]); \
        acc[1][1] = MFMA(A##1, B##3, acc[1][1]); \
        acc[2][0] = MFMA(A##2, B##2, acc[2][0]); \
        acc[2][1] = MFMA(A##2, B##3, acc[2][1]); \
        acc[3][0] = MFMA(A##3, B##2, acc[3][0]); \
        acc[3][1] = MFMA(A##3, B##3, acc[3][1]); } while (0)

    v16f vzero;
#pragma unroll
    for (int r = 0; r < 16; ++r) vzero[r] = 0.0f;
    v16f acc[4][2];
#pragma unroll
    for (int a = 0; a < 4; ++a)
#pragma unroll
        for (int b = 0; b < 2; ++b) acc[a][b] = vzero;

    float b1d[2] = {-3.0e38f, -3.0e38f}, b2d[2] = {-3.0e38f, -3.0e38f};
    int   b1i[2] = {0x7fffffff, 0x7fffffff};

    v8h Aa0, Aa1, Aa2, Aa3, Ab0, Ab1, Ab2, Ab3;
    v8h Ba0, Ba1, Ba2, Ba3, Bb0, Bb1, Bb2, Bb3;

    LOAD_A(Aa, 0); READ_B(Ba, 0);

#pragma unroll 1
    for (int g = 0; g < NCHUNK; g += 2) {
        LOAD_A(Ab, g + 1); READ_B(Bb, g + 1);
        MFMA16(Aa, Ba);
        if (g + 2 < NCHUNK) { LOAD_A(Aa, g + 2); READ_B(Ba, g + 2); }
        MFMA16(Ab, Bb);

        if ((g & 15) == 14) {       // ---- fold kci into running top-2, reset acc
            const int kci = g >> 4;
            const float* bp = b2 + (kci << 10) + wid * 128 + 4 * lhalf;
#pragma unroll
            for (int fm = 0; fm < 4; ++fm) {
                float4 q0 = *(const float4*)(bp + fm * 32);
                float4 q1 = *(const float4*)(bp + fm * 32 + 8);
                float4 q2 = *(const float4*)(bp + fm * 32 + 16);
                float4 q3 = *(const float4*)(bp + fm * 32 + 24);
                float bw[16] = {q0.x, q0.y, q0.z, q0.w, q1.x, q1.y, q1.z, q1.w,
                                q2.x, q2.y, q2.z, q2.w, q3.x, q3.y, q3.z, q3.w};
                const int kbase = (kci << 10) + wid * 128 + fm * 32 + 4 * lhalf;
#pragma unroll
                for (int j = 0; j < 2; ++j) {
#pragma unroll
                    for (int r = 0; r < 16; ++r) {
                        float sv = fmaf(-0.5f, bw[r], acc[fm][j][r]);
                        int k = kbase + (r & 3) + 8 * (r >> 2);
                        bool better = (sv > b1d[j]) || (sv == b1d[j] && k < b1i[j]);
                        b2d[j] = better ? b1d[j] : fmaxf(b2d[j], sv);
                        b1d[j] = better ? sv : b1d[j];
                        b1i[j] = better ? k : b1i[j];
                    }
                    acc[fm][j] = vzero;
                }
            }
        }
    }

    // ---- merge lane halves (same token lives in lane and lane^32)
#pragma unroll
    for (int j = 0; j < 2; ++j) {
        float o1 = __shfl_xor(b1d[j], 32);
        float o2 = __shfl_xor(b2d[j], 32);
        int   oi = __shfl_xor(b1i[j], 32);
        bool ow = (o1 > b1d[j]) || (o1 == b1d[j] && oi < b1i[j]);
        float nb2 = fmaxf(fminf(b1d[j], o1), fmaxf(b2d[j], o2));
        b1i[j] = ow ? oi : b1i[j];
        b1d[j] = fmaxf(b1d[j], o1);
        b2d[j] = nb2;
    }

    __syncthreads();
    float* f1 = (float*)Xh;          // [8 waves][64 tokens]
    float* f2 = f1 + 512;
    int*   fi = (int*)(f2 + 512);
    if (lane < 32) {
#pragma unroll
        for (int j = 0; j < 2; ++j) {
            int idx = wid * 64 + j * 32 + l31;
            f1[idx] = b1d[j]; f2[idx] = b2d[j]; fi[idx] = b1i[j];
        }
    }
    __syncthreads();
    if (tid < BN) {
        float s1 = -3.0e38f, s2 = -3.0e38f; int si = 0x7fffffff;
#pragma unroll
        for (int w = 0; w < 8; ++w) {
            float c1 = f1[w * 64 + tid], c2 = f2[w * 64 + tid];
            int  ci1 = fi[w * 64 + tid];
            bool ow = (c1 > s1) || (c1 == s1 && ci1 < si);
            float nb2 = fmaxf(fminf(s1, c1), fmaxf(s2, c2));
            si = ow ? ci1 : si; s1 = fmaxf(s1, c1); s2 = nb2;
        }
        int n = n0 + tid;
        bestIdx[n] = si;
        if (s1 - s2 < MARGIN_S) {            // near-tie under fp16 error -> exact re-resolve
            int pos = atomicAdd(flagCnt, 1);
            flagList[pos] = n;
        }
    }
}

// ---------------------------------------------------------------- fp64 exact refine
__global__ void refine_kernel(const float* __restrict__ x, const float* __restrict__ cb,
                              const int* __restrict__ flagCnt, const int* __restrict__ flagList,
                              int* __restrict__ bestIdx)
{
    __shared__ float  xr[DIM];
    __shared__ double rd[256];
    __shared__ int    ri[256];
    const int tid = threadIdx.x;
    const int cnt = *flagCnt;
    for (int f = blockIdx.x; f < cnt; f += gridDim.x) {
        const int n = flagList[f];
        __syncthreads();
        if (tid < DIM / 4) {
            float4 v = reinterpret_cast<const float4*>(x + (size_t)n * DIM)[tid];
            xr[tid * 4 + 0] = v.x; xr[tid * 4 + 1] = v.y;
            xr[tid * 4 + 2] = v.z; xr[tid * 4 + 3] = v.w;
        }
        __syncthreads();
        double best = 1e300; int bi = K_CB;
        for (int k = tid; k < K_CB; k += 256) {
            const float* crow = cb + (size_t)k * DIM;
            double dot = 0.0, nb = 0.0;
            for (int d = 0; d < DIM; d += 4) {
                float4 cv = *reinterpret_cast<const float4*>(crow + d);
                dot += (double)cv.x * xr[d]     + (double)cv.y * xr[d + 1]
                     + (double)cv.z * xr[d + 2] + (double)cv.w * xr[d + 3];
                nb  += (double)cv.x * cv.x + (double)cv.y * cv.y
                     + (double)cv.z * cv.z + (double)cv.w * cv.w;
            }
            double dist = nb - 2.0 * dot;
            if (dist < best || (dist == best && k < bi)) { best = dist; bi = k; }
        }
        rd[tid] = best; ri[tid] = bi;
        __syncthreads();
        for (int s = 128; s > 0; s >>= 1) {
            if (tid < s) {
                double od = rd[tid + s]; int oi = ri[tid + s];
                if (od < rd[tid] || (od == rd[tid] && oi < ri[tid])) { rd[tid] = od; ri[tid] = oi; }
            }
            __syncthreads();
        }
        if (tid == 0) bestIdx[n] = ri[0];
        __syncthreads();
    }
}

// ---------------------------------------------------------------- gather out rows
__global__ void gather_kernel(const float* __restrict__ cb, const int* __restrict__ bestIdx,
                              float* __restrict__ out)
{
    int t = blockIdx.x * 256 + threadIdx.x;
    int n = t >> 6, f4 = t & 63;
    int k = bestIdx[n];
    reinterpret_cast<float4*>(out)[t] =
        reinterpret_cast<const float4*>(cb + (size_t)k * DIM)[f4];
}

extern "C" void kernel_launch(void* const* d_in, const int* in_sizes, int n_in,
                              void* d_out, int out_size, void* d_ws, size_t ws_size,
                              hipStream_t stream)
{
    const float* x  = (const float*)d_in[0];
    const float* cb = (const float*)d_in[1];
    float* out = (float*)d_out;

    char* ws = (char*)d_ws;
    ushort_t* cbws    = (ushort_t*)ws;                      // 64*32768 = 2,097,152 B
    float*    b2      = (float*)(ws + 2097152);             // 16 KB
    int*      bestIdx = (int*)(ws + 2113536);               // 256 KB
    int*      flagCnt = (int*)(ws + 2375680);               // 16 B
    int*      flagList= (int*)(ws + 2375696);               // 256 KB

    hipMemsetAsync(flagCnt, 0, sizeof(int), stream);
    b2_kernel    <<<dim3(1024), dim3(256), 0, stream>>>(cb, b2);
    pack_cb      <<<dim3(512),  dim3(256), 0, stream>>>(cb, cbws);
    argmin_kernel<<<dim3(N_TOK / BN), dim3(512), 0, stream>>>(x, cbws, b2, bestIdx, flagCnt, flagList);
    refine_kernel<<<dim3(256),  dim3(256), 0, stream>>>(x, cb, flagCnt, flagList, bestIdx);
    gather_kernel<<<dim3(N_TOK * 64 / 256), dim3(256), 0, stream>>>(cb, bestIdx, out);
}